// Round 14
// baseline (227.391 us; speedup 1.0000x reference)
//
#include <hip/hip_runtime.h>

#define N_AUTHORS 50000
#define N_PAPERS  100000
#define N_NODES   150000
#define N_EDGES   1200000
#define EMB       64

#define BSHIFT 10
#define K_B    ((N_NODES + 1023) >> 10)           // 147 row-buckets (1024 rows each)
#define CHUNK  4096                               // edges per A-block
#define NBLK_A ((N_EDGES + CHUNK - 1) / CHUNK)    // 293
#define NSC    (K_B * NBLK_A)                     // 43071 (bucket-major counts)
#define NBS1   ((NSC + 1023) / 1024)              // 43 L1-scan blocks

// bf16 helpers (plain ushort storage)
__device__ __forceinline__ float bf2f(ushort u) {
    return __uint_as_float(((unsigned)u) << 16);
}
__device__ __forceinline__ ushort f2bf(float f) {   // round-to-nearest-even
    unsigned u = __float_as_uint(f);
    return (ushort)((u + 0x7fffu + ((u >> 16) & 1u)) >> 16);
}
#define bfLO(u) __uint_as_float((u) << 16)
#define bfHI(u) __uint_as_float((u) & 0xffff0000u)

// ---------------- init: ego(f32,out) + ego(bf16 scratch) --------------------
__global__ void lgcn_init(const float* __restrict__ a,
                          const float* __restrict__ p,
                          float* __restrict__ ego_out,
                          ushort* __restrict__ x0) {
    size_t i = (size_t)blockIdx.x * blockDim.x + threadIdx.x;  // float4 index
    const size_t n4  = (size_t)N_NODES  * EMB / 4;
    const size_t au4 = (size_t)N_AUTHORS * EMB / 4;
    if (i >= n4) return;
    float4 v = (i < au4) ? ((const float4*)a)[i] : ((const float4*)p)[i - au4];
    ((float4*)ego_out)[i] = v;
    ushort4 b;
    b.x = f2bf(v.x); b.y = f2bf(v.y); b.z = f2bf(v.z); b.w = f2bf(v.w);
    ((ushort4*)x0)[i] = b;
}

// ---------------- bucket-major per-block histogram --------------------------
__global__ void lgcn_a0_hist(const int* __restrict__ rows,
                             unsigned* __restrict__ counts) {
    __shared__ unsigned h[K_B];
    int t = threadIdx.x;
    for (int i = t; i < K_B; i += blockDim.x) h[i] = 0;
    __syncthreads();
    int base = blockIdx.x * CHUNK;
    int end  = base + CHUNK; if (end > N_EDGES) end = N_EDGES;
    for (int e = base + t; e < end; e += blockDim.x)
        atomicAdd(&h[rows[e] >> BSHIFT], 1u);
    __syncthreads();
    for (int i = t; i < K_B; i += blockDim.x)
        counts[(size_t)i * NBLK_A + blockIdx.x] = h[i];
}

// ---------------- 2-level parallel exclusive scan over NSC entries ----------
__global__ void lgcn_scan_l1(const unsigned* __restrict__ counts,
                             unsigned* __restrict__ scanned,
                             unsigned* __restrict__ btot) {
    __shared__ unsigned s[1024];
    int t = threadIdx.x;
    int i = blockIdx.x * 1024 + t;
    unsigned v = (i < NSC) ? counts[i] : 0u;
    s[t] = v;
    __syncthreads();
    for (int d = 1; d < 1024; d <<= 1) {
        unsigned u = (t >= d) ? s[t - d] : 0u;
        __syncthreads();
        s[t] += u;
        __syncthreads();
    }
    if (i < NSC) scanned[i] = s[t] - v;     // exclusive within block
    if (t == 1023) btot[blockIdx.x] = s[1023];
}

__global__ void lgcn_scan_l2(const unsigned* __restrict__ btot,
                             unsigned* __restrict__ btot_ex) {
    __shared__ unsigned s[64];
    int t = threadIdx.x;                     // 64 threads
    unsigned v = (t < NBS1) ? btot[t] : 0u;
    s[t] = v;
    __syncthreads();
    for (int d = 1; d < 64; d <<= 1) {
        unsigned u = (t >= d) ? s[t - d] : 0u;
        __syncthreads();
        s[t] += u;
        __syncthreads();
    }
    btot_ex[t] = s[t] - v;                   // exclusive
}

__device__ __forceinline__ unsigned scan_at(const unsigned* scanned,
                                            const unsigned* btot_ex, unsigned idx) {
    return scanned[idx] + btot_ex[idx >> 10];
}

// ---------------- A1: bin edges into EXCLUSIVE per-(block,bucket) runs ------
// Stage record packs (rowlo<<18 | col) in .x, val in .y.
__global__ void lgcn_a1_bin(const int* __restrict__ rows,
                            const int* __restrict__ cols,
                            const float* __restrict__ vals,
                            const unsigned* __restrict__ scanned,
                            const unsigned* __restrict__ btot_ex,
                            float2* __restrict__ stage) {
    __shared__ unsigned cur[K_B];
    int t = threadIdx.x;
    for (int i = t; i < K_B; i += blockDim.x)
        cur[i] = scan_at(scanned, btot_ex, (unsigned)i * NBLK_A + blockIdx.x);
    __syncthreads();
    int base = blockIdx.x * CHUNK;
    int end  = base + CHUNK; if (end > N_EDGES) end = N_EDGES;
    for (int e = base + t; e < end; e += blockDim.x) {
        int r = rows[e];
        unsigned pos = atomicAdd(&cur[r >> BSHIFT], 1u);
        unsigned packed = ((unsigned)(r & 1023) << 18) | (unsigned)cols[e];
        stage[pos] = make_float2(__uint_as_float(packed), vals[e]);
    }
}

// ---------------- B: per-bucket place; self-counts rows; emits row_start ----
__global__ void lgcn_place(const unsigned* __restrict__ scanned,
                           const unsigned* __restrict__ btot_ex,
                           const float2* __restrict__ stage,
                           float2* __restrict__ se,
                           unsigned* __restrict__ row_start) {
    __shared__ unsigned cur[1 << BSHIFT];
    __shared__ unsigned tsum[256];
    int b  = blockIdx.x;
    int rb = b << BSHIFT;
    int nrows = N_NODES - rb; if (nrows > (1 << BSHIFT)) nrows = 1 << BSHIFT;
    int t = threadIdx.x;

    unsigned base  = scan_at(scanned, btot_ex, (unsigned)b * NBLK_A);
    unsigned span1 = (b + 1 < K_B)
                   ? scan_at(scanned, btot_ex, (unsigned)(b + 1) * NBLK_A)
                   : N_EDGES;

    // pass 1: count this bucket's rows from the staged records (L2-hot span)
    for (int i = t; i < (1 << BSHIFT); i += 256) cur[i] = 0;
    __syncthreads();
    for (unsigned p = base + t; p < span1; p += 256)
        atomicAdd(&cur[__float_as_uint(stage[p].x) >> 18], 1u);
    __syncthreads();

    // block scan of the 1024 counts (4 per thread) -> cursors + row_start
    unsigned c[4], s = 0;
#pragma unroll
    for (int k = 0; k < 4; ++k) { c[k] = cur[t * 4 + k]; s += c[k]; }
    tsum[t] = s;
    __syncthreads();
    for (int d = 1; d < 256; d <<= 1) {
        unsigned u = (t >= d) ? tsum[t - d] : 0u;
        __syncthreads();
        tsum[t] += u;
        __syncthreads();
    }
    unsigned run = base + (tsum[t] - s);
    __syncthreads();            // everyone done reading cur before overwrite
#pragma unroll
    for (int k = 0; k < 4; ++k) {
        int i = t * 4 + k;
        cur[i] = run;
        if (i < nrows) row_start[rb + i] = run;
        run += c[k];
    }
    if (b == K_B - 1 && t == 0) row_start[N_NODES] = N_EDGES;
    __syncthreads();

    // pass 2: place into row-sorted se (writes land in ~65KB L2 window)
    for (unsigned p = base + t; p < span1; p += 256) {
        float2 v = stage[p];
        unsigned u = __float_as_uint(v.x);
        unsigned pos = atomicAdd(&cur[u >> 18], 1u);
        se[pos] = make_float2(__int_as_float((int)(u & 0x3FFFFu)), v.y);
    }
}

// ---------------- SpMM: one wave per 4 rows, 8-lane edge groups -------------
// Lane l: edge slot g=l>>3, dims d8=(l&7)*8.  All four rows' first 8-edge
// batches issue back-to-back: 4 independent gather wave-instructions (plus 4
// se loads) in flight before any dependent ALU.  FINAL fuses the merge:
// out = 0.25*(bf16ego + y1 + y2 + A*x).
template <int FINAL>
__global__ void lgcn_spmm(const unsigned* __restrict__ rs,
                          const float2* __restrict__ se,
                          const ushort* __restrict__ x,
                          ushort* __restrict__ y,
                          const ushort* __restrict__ egob,
                          const ushort* __restrict__ y1,
                          const ushort* __restrict__ y2,
                          float* __restrict__ out) {
    int w    = blockIdx.x * (blockDim.x >> 6) + (threadIdx.x >> 6);
    int lane = threadIdx.x & 63;
    int r0   = w << 2;
    if (r0 >= N_NODES) return;
    unsigned s0 = rs[r0];
    unsigned s1 = rs[r0 + 1];
    unsigned s2 = rs[r0 + 2];
    unsigned s3 = rs[r0 + 3];
    unsigned s4 = rs[r0 + 4];
    const int g  = lane >> 3;
    const int d8 = (lane & 7) << 3;
    float acc[4][8];
#pragma unroll
    for (int r = 0; r < 4; ++r)
#pragma unroll
        for (int k = 0; k < 8; ++k) acc[r][k] = 0.f;

#define BATCH8(JB, END, R)                                                    \
    {                                                                         \
        unsigned idx = (JB) + g;                                              \
        float2 e;                                                             \
        if (idx < (END)) e = se[idx];                                         \
        else { e.x = __int_as_float(0); e.y = 0.f; }                          \
        const uint4 xv = *(const uint4*)(x + ((size_t)__float_as_int(e.x) << 6) + d8); \
        acc[R][0] += e.y * bfLO(xv.x); acc[R][1] += e.y * bfHI(xv.x);         \
        acc[R][2] += e.y * bfLO(xv.y); acc[R][3] += e.y * bfHI(xv.y);         \
        acc[R][4] += e.y * bfLO(xv.z); acc[R][5] += e.y * bfHI(xv.z);         \
        acc[R][6] += e.y * bfLO(xv.w); acc[R][7] += e.y * bfHI(xv.w);         \
    }

    // 4 rows' first batches: 4 independent gather chains in flight
    BATCH8(s0, s1, 0)
    BATCH8(s1, s2, 1)
    BATCH8(s2, s3, 2)
    BATCH8(s3, s4, 3)
    unsigned j0 = s0 + 8, j1 = s1 + 8, j2 = s2 + 8, j3 = s3 + 8;
    while (j0 < s1) { BATCH8(j0, s1, 0) j0 += 8; }   // deg>8: ~46% of rows
    while (j1 < s2) { BATCH8(j1, s2, 1) j1 += 8; }
    while (j2 < s3) { BATCH8(j2, s3, 2) j2 += 8; }
    while (j3 < s4) { BATCH8(j3, s4, 3) j3 += 8; }
#undef BATCH8

    // reduce across the 8 edge slots (xor 8/16/32)
#pragma unroll
    for (int r = 0; r < 4; ++r)
#pragma unroll
        for (int k = 0; k < 8; ++k) {
            float v = acc[r][k];
            v += __shfl_xor(v, 8, 64);
            v += __shfl_xor(v, 16, 64);
            v += __shfl_xor(v, 32, 64);
            acc[r][k] = v;
        }

    if (g == 0) {
#pragma unroll
        for (int r = 0; r < 4; ++r) {
            size_t o = ((size_t)(r0 + r) << 6) + d8;
            if (FINAL) {
                uint4 ue = *(const uint4*)(egob + o);
                uint4 u1 = *(const uint4*)(y1 + o);
                uint4 u2 = *(const uint4*)(y2 + o);
                float4 lo, hi;
                lo.x = 0.25f * (bfLO(ue.x) + bfLO(u1.x) + bfLO(u2.x) + acc[r][0]);
                lo.y = 0.25f * (bfHI(ue.x) + bfHI(u1.x) + bfHI(u2.x) + acc[r][1]);
                lo.z = 0.25f * (bfLO(ue.y) + bfLO(u1.y) + bfLO(u2.y) + acc[r][2]);
                lo.w = 0.25f * (bfHI(ue.y) + bfHI(u1.y) + bfHI(u2.y) + acc[r][3]);
                hi.x = 0.25f * (bfLO(ue.z) + bfLO(u1.z) + bfLO(u2.z) + acc[r][4]);
                hi.y = 0.25f * (bfHI(ue.z) + bfHI(u1.z) + bfHI(u2.z) + acc[r][5]);
                hi.z = 0.25f * (bfLO(ue.w) + bfLO(u1.w) + bfLO(u2.w) + acc[r][6]);
                hi.w = 0.25f * (bfHI(ue.w) + bfHI(u1.w) + bfHI(u2.w) + acc[r][7]);
                *(float4*)(out + o)     = lo;
                *(float4*)(out + o + 4) = hi;
            } else {
                uint4 ov;
                ov.x = (unsigned)f2bf(acc[r][0]) | ((unsigned)f2bf(acc[r][1]) << 16);
                ov.y = (unsigned)f2bf(acc[r][2]) | ((unsigned)f2bf(acc[r][3]) << 16);
                ov.z = (unsigned)f2bf(acc[r][4]) | ((unsigned)f2bf(acc[r][5]) << 16);
                ov.w = (unsigned)f2bf(acc[r][6]) | ((unsigned)f2bf(acc[r][7]) << 16);
                *(uint4*)(y + o) = ov;
            }
        }
    }
}

extern "C" void kernel_launch(void* const* d_in, const int* in_sizes, int n_in,
                              void* d_out, int out_size, void* d_ws, size_t ws_size,
                              hipStream_t stream) {
    const float* author = (const float*)d_in[0];
    const float* paper  = (const float*)d_in[1];
    const int*   rows   = (const int*)d_in[2];
    const int*   cols   = (const int*)d_in[3];
    const float* vals   = (const float*)d_in[4];

    float* ego_out = (float*)d_out;                           // 150000*64 f32
    float* acc     = (float*)d_out + (size_t)N_NODES * EMB;   // author||paper f32

    // workspace layout (~77.9 MB)
    char* w = (char*)d_ws;
    float2*   se        = (float2*)w;   w += (size_t)N_EDGES * sizeof(float2);       // 9.6 MB
    float2*   stage     = (float2*)w;   w += (size_t)N_EDGES * sizeof(float2);       // 9.6 MB
    ushort*   xbE       = (ushort*)w;   w += (size_t)N_NODES * EMB * sizeof(ushort); // 19.2 MB
    ushort*   xb1       = (ushort*)w;   w += (size_t)N_NODES * EMB * sizeof(ushort); // 19.2 MB (y1)
    ushort*   xb2       = (ushort*)w;   w += (size_t)N_NODES * EMB * sizeof(ushort); // 19.2 MB (y2)
    unsigned* row_start = (unsigned*)w; w += (size_t)(N_NODES + 1) * 4;              // 0.6 MB
    unsigned* bcounts   = (unsigned*)w; w += (size_t)NSC * 4;                        // 172 KB
    unsigned* bscanned  = (unsigned*)w; w += (size_t)NSC * 4;                        // 172 KB
    unsigned* btot      = (unsigned*)w; w += 64 * 4;
    unsigned* btot_ex   = (unsigned*)w; w += 64 * 4;

    const int BLK = 256;
    const int g_vec  = (int)(((size_t)N_NODES * EMB / 4 + BLK - 1) / BLK);
    const int g_spmm = ((N_NODES / 4) + 3) / 4;       // 4 rows/wave, 4 waves/block

    // init: ego (f32, out) + ego (bf16 scratch)
    lgcn_init<<<g_vec, BLK, 0, stream>>>(author, paper, ego_out, xbE);

    // bucket-major (block,bucket) histogram + 2-level scan
    lgcn_a0_hist<<<NBLK_A, BLK, 0, stream>>>(rows, bcounts);
    lgcn_scan_l1<<<NBS1, 1024, 0, stream>>>(bcounts, bscanned, btot);
    lgcn_scan_l2<<<1, 64, 0, stream>>>(btot, btot_ex);

    // bin into exclusive staging runs, then place (also emits row_start)
    lgcn_a1_bin<<<NBLK_A, BLK, 0, stream>>>(rows, cols, vals, bscanned, btot_ex, stage);
    lgcn_place<<<K_B, BLK, 0, stream>>>(bscanned, btot_ex, stage, se, row_start);

    // 3 propagation layers; last one fuses the merge (bf16 ego stream)
    lgcn_spmm<0><<<g_spmm, BLK, 0, stream>>>(row_start, se, xbE, xb1, nullptr, nullptr, nullptr, nullptr);
    lgcn_spmm<0><<<g_spmm, BLK, 0, stream>>>(row_start, se, xb1, xb2, nullptr, nullptr, nullptr, nullptr);
    lgcn_spmm<1><<<g_spmm, BLK, 0, stream>>>(row_start, se, xb2, nullptr, xbE, xb1, xb2, acc);
}